// Round 16
// baseline (243.778 us; speedup 1.0000x reference)
//
#include <hip/hip_runtime.h>

// Problem constants (match reference)
#define N_NODES 40000
#define ISIZE   64
#define KNN     24
#define NE      (N_NODES * KNN)      // 960000 edges (= E_ADJ as well)
#define OMEGA   0.9f
#define CAP     64                   // per-node bucket capacity (max deg ~46)
#define NBUCK   80                   // buckets of 512 nodes (idx>>9)
#define BCAP    16384                // adj edges per bucket capacity (mean 12288)
#define JBCAP   16384                // learner edges per bucket capacity
#define EPT     8                    // edges per thread in bin pass

// ---- bf16 helpers (storage-only precision; all math in fp32) -------------
__device__ __forceinline__ float bf2f(unsigned short s) {
    return __uint_as_float(((unsigned)s) << 16);
}
__device__ __forceinline__ unsigned short f2bf(float f) {  // round-nearest-even
    unsigned u = __float_as_uint(f);
    u += 0x7fffu + ((u >> 16) & 1u);
    return (unsigned short)(u >> 16);
}
__device__ __forceinline__ float bflo(unsigned u) { return __uint_as_float(u << 16); }
__device__ __forceinline__ float bfhi(unsigned u) { return __uint_as_float(u & 0xffff0000u); }
__device__ __forceinline__ unsigned pack2(float lo, float hi) {
    return (unsigned)f2bf(lo) | ((unsigned)f2bf(hi) << 16);
}
__device__ __forceinline__ float dot8(uint4 a, uint4 b) {
    return bflo(a.x) * bflo(b.x) + bfhi(a.x) * bfhi(b.x)
         + bflo(a.y) * bflo(b.y) + bfhi(a.y) * bfhi(b.y)
         + bflo(a.z) * bflo(b.z) + bfhi(a.z) * bfhi(b.z)
         + bflo(a.w) * bflo(b.w) + bfhi(a.w) * bfhi(b.w);
}

// ---- mega front end: gemm layer1 | bin both edge sets | reverse scan -----
// Node feature rows are stored MERGED: 64 bf16 = 128 B per row (uint4 x 8).
__global__ void k_mega1(const float* __restrict__ X, const float* __restrict__ W,
                        unsigned short* __restrict__ Y,
                        const int* __restrict__ row, const int* __restrict__ col,
                        const int* __restrict__ j_idx,
                        int* __restrict__ bcnt, unsigned* __restrict__ bbuf,
                        unsigned* __restrict__ ovf2, int* __restrict__ ovf2_cnt,
                        int* __restrict__ jbcnt, unsigned* __restrict__ jbbuf,
                        unsigned* __restrict__ jovf, int* __restrict__ jovf_cnt,
                        unsigned char* __restrict__ revb) {
    __shared__ float sW[64 * 64];    // gemm: W tile | bin: lcnt/lbase overlay
    __shared__ float sX[32 * 64];
    const int GB  = N_NODES / 32;                          // 1250 gemm blocks
    const int NBA = (NE + 256 * EPT - 1) / (256 * EPT);    // 469 bin blocks per set
    int bx = blockIdx.x;
    int tid = threadIdx.x;
    if (bx < GB) {
        // ---- GEMM layer 1: rows bx*32.., merged bf16 output ----
        int row0 = bx * 32;
        for (int t = tid; t < 1024; t += 256)
            ((float4*)sW)[t] = ((const float4*)W)[t];
        for (int t = tid; t < 512; t += 256)
            ((float4*)sX)[t] = ((const float4*)(X + row0 * 64))[t];
        __syncthreads();
        int cc = tid & 63;
        int rl = tid >> 6;
        for (int r = rl; r < 32; r += 4) {
            float acc = 0.0f;
#pragma unroll
            for (int kk = 0; kk < 64; kk++) acc += sX[r * 64 + kk] * sW[kk * 64 + cc];
            Y[(row0 + r) * 64 + cc] = f2bf(acc);
        }
    } else if (bx < GB + 2 * NBA) {
        // ---- bin edges: adj by col (r<<16|c), learner by j ((j&511)<<20|e)
        int* lcnt  = (int*)sW;
        int* lbase = lcnt + NBUCK;
        int blk = bx - GB;
        bool adj = blk < NBA;
        if (!adj) blk -= NBA;
        for (int b = tid; b < NBUCK; b += 256) lcnt[b] = 0;
        __syncthreads();
        int e0 = blk * (256 * EPT);
        int myslot[EPT]; int myb[EPT]; unsigned myp[EPT];
        for (int k = 0; k < EPT; k++) {
            int e = e0 + k * 256 + tid;
            if (e < NE) {
                int b; unsigned p;
                if (adj) { int r = row[e], c = col[e]; b = c >> 9; p = ((unsigned)r << 16) | (unsigned)c; }
                else     { int j = j_idx[e];           b = j >> 9; p = ((unsigned)(j & 511) << 20) | (unsigned)e; }
                myb[k] = b; myp[k] = p;
                myslot[k] = atomicAdd(&lcnt[b], 1);
            } else myb[k] = -1;
        }
        __syncthreads();
        int* gcnt = adj ? bcnt : jbcnt;
        for (int b = tid; b < NBUCK; b += 256)
            lbase[b] = (lcnt[b] > 0) ? atomicAdd(&gcnt[b], lcnt[b]) : 0;
        __syncthreads();
        unsigned* gbuf = adj ? bbuf : jbbuf;
        unsigned* govf = adj ? ovf2 : jovf;
        int* gocnt = adj ? ovf2_cnt : jovf_cnt;
        for (int k = 0; k < EPT; k++) {
            if (myb[k] < 0) continue;
            int pos = lbase[myb[k]] + myslot[k];
            if (pos < BCAP) gbuf[myb[k] * BCAP + pos] = myp[k];
            else { int p = atomicAdd(gocnt, 1); govf[p] = myp[k]; }
        }
    } else {
        // ---- reverse-edge match: 1 thread/edge, 6 x uint4 over j's slice -
        int e = (bx - GB - 2 * NBA) * 256 + tid;   // NE threads
        int i = e / KNN;
        int j = j_idx[e];
        const uint4* jj4 = (const uint4*)(j_idx + j * KNN);  // 96B rows: 16B-aligned
        int rt = 255;
#pragma unroll
        for (int k = 5; k >= 0; k--) {             // descending so min index wins
            uint4 u = jj4[k];
            if ((int)u.w == i) rt = 4 * k + 3;
            if ((int)u.z == i) rt = 4 * k + 2;
            if ((int)u.y == i) rt = 4 * k + 1;
            if ((int)u.x == i) rt = 4 * k + 0;
        }
        revb[e] = (unsigned char)rt;
    }
}

// ---- per-bucket scatter: LDS slot assignment, NO global atomics ----------
__global__ void k_scatter3(const unsigned* __restrict__ bbuf, const int* __restrict__ bcnt,
                           int* __restrict__ cnt, unsigned short* __restrict__ ebuf,
                           unsigned* __restrict__ ovf, int* __restrict__ ovf_cnt,
                           const unsigned* __restrict__ ovf2, const int* __restrict__ ovf2_cnt) {
    __shared__ int lcnt2[512];
    int b = blockIdx.x;
    int tid = threadIdx.x;                   // 1024 threads
    if (tid < 512) lcnt2[tid] = 0;
    __syncthreads();
    int n = min(bcnt[b], BCAP);
    for (int idx = tid; idx < n; idx += 1024) {
        unsigned p = bbuf[b * BCAP + idx];
        int c = (int)(p & 0xffffu), r = (int)(p >> 16);
        int slot = atomicAdd(&lcnt2[c & 511], 1);
        if (slot < CAP) ebuf[c * CAP + slot] = (unsigned short)r;
        else { int q = atomicAdd(ovf_cnt, 1); ovf[q] = p; }
    }
    int m = ovf2_cnt[0];                     // adj bin overflow (normally 0)
    for (int idx = tid; idx < m; idx += 1024) {
        unsigned p = ovf2[idx];
        int c = (int)(p & 0xffffu), r = (int)(p >> 16);
        if ((c >> 9) != b) continue;
        int slot = atomicAdd(&lcnt2[c & 511], 1);
        if (slot < CAP) ebuf[c * CAP + slot] = (unsigned short)r;
        else { int q = atomicAdd(ovf_cnt, 1); ovf[q] = p; }
    }
    __syncthreads();
    if (tid < 512) {
        int node = b * 512 + tid;
        if (node < N_NODES) cnt[node] = lcnt2[tid];   // full degree (incl. >CAP)
    }
}

// ---- fused layer-1: pull-agg + self + bias + ReLU, then xW2 GEMM ---------
// 1024 threads = 16 waves = 32 nodes per block (2 nodes/wave).
// Merged 128B rows: per gathered row, 2 ADJACENT uint4 loads (one L2 line).
__global__ void __launch_bounds__(1024, 1)
k_aggemm1(const uint4* __restrict__ Aq, const float* __restrict__ W2,
          unsigned short* __restrict__ C,
          const int* __restrict__ cnt,
          const unsigned short* __restrict__ ebuf, const float* __restrict__ bias,
          const unsigned* __restrict__ ovf, const int* __restrict__ ovf_cnt) {
    __shared__ float sW[64 * 64];     // 16 KB
    __shared__ float sB[32 * 64];     // 8 KB
    int tid  = threadIdx.x;
    int lane = tid & 63;
    int half = lane >> 5, sl = lane & 31;
    int nl = (tid >> 6) * 2 + half;   // local node 0..31
    int n  = blockIdx.x * 32 + nl;    // exact fit: 1250*32 == N_NODES

    // stage W2 (coalesced; no dependency until gemm phase)
    ((float4*)sW)[tid] = ((const float4*)W2)[tid];

    int deg = cnt[n];
    int bucketed = min(deg, CAP);
    int nb0 = min(bucketed, 32);
    int nb1 = bucketed - nb0;

    int   r0v = 0, r1v = 0;
    float d0v = 0.0f, d1v = 0.0f;
    if (sl < nb0) { r0v = (int)ebuf[n * CAP + sl];      d0v = rsqrtf(1.0f + (float)cnt[r0v]); }
    if (sl < nb1) { r1v = (int)ebuf[n * CAP + 32 + sl]; d1v = rsqrtf(1.0f + (float)cnt[r1v]); }

    int g = sl >> 2;          // row subgroup 0..7
    int f = sl & 3;           // uint4 quarter

    float a[16];
#pragma unroll
    for (int k = 0; k < 16; k++) a[k] = 0.f;
    int np0 = (nb0 + 7) >> 3;
    int np1 = (nb1 + 7) >> 3;

#pragma unroll 4
    for (int d = 0; d < np0; d++) {
        int   q = 8 * d + g;
        int   r = __shfl(r0v, q, 32);
        float c = __shfl(d0v, q, 32);
        uint4 u0 = Aq[r * 8 + f];
        uint4 u1 = Aq[r * 8 + 4 + f];
        a[0]  += c * bflo(u0.x); a[1]  += c * bfhi(u0.x);
        a[2]  += c * bflo(u0.y); a[3]  += c * bfhi(u0.y);
        a[4]  += c * bflo(u0.z); a[5]  += c * bfhi(u0.z);
        a[6]  += c * bflo(u0.w); a[7]  += c * bfhi(u0.w);
        a[8]  += c * bflo(u1.x); a[9]  += c * bfhi(u1.x);
        a[10] += c * bflo(u1.y); a[11] += c * bfhi(u1.y);
        a[12] += c * bflo(u1.z); a[13] += c * bfhi(u1.z);
        a[14] += c * bflo(u1.w); a[15] += c * bfhi(u1.w);
    }
#pragma unroll 4
    for (int d = 0; d < np1; d++) {
        int   q = 8 * d + g;
        int   r = __shfl(r1v, q, 32);
        float c = __shfl(d1v, q, 32);
        uint4 u0 = Aq[r * 8 + f];
        uint4 u1 = Aq[r * 8 + 4 + f];
        a[0]  += c * bflo(u0.x); a[1]  += c * bfhi(u0.x);
        a[2]  += c * bflo(u0.y); a[3]  += c * bfhi(u0.y);
        a[4]  += c * bflo(u0.z); a[5]  += c * bfhi(u0.z);
        a[6]  += c * bflo(u0.w); a[7]  += c * bfhi(u0.w);
        a[8]  += c * bflo(u1.x); a[9]  += c * bfhi(u1.x);
        a[10] += c * bflo(u1.y); a[11] += c * bfhi(u1.y);
        a[12] += c * bflo(u1.z); a[13] += c * bfhi(u1.z);
        a[14] += c * bflo(u1.w); a[15] += c * bfhi(u1.w);
    }
    if (deg > CAP) {                         // CAP overflow (normally none)
        int m = ovf_cnt[0];
        for (int k2 = 0; k2 < m; k2++) {
            unsigned p = ovf[k2];
            if ((int)(p & 0xffffu) == n && g == 0) {
                int r = (int)(p >> 16);
                float c = rsqrtf(1.0f + (float)cnt[r]);
                uint4 u0 = Aq[r * 8 + f], u1 = Aq[r * 8 + 4 + f];
                a[0]  += c * bflo(u0.x); a[1]  += c * bfhi(u0.x);
                a[2]  += c * bflo(u0.y); a[3]  += c * bfhi(u0.y);
                a[4]  += c * bflo(u0.z); a[5]  += c * bfhi(u0.z);
                a[6]  += c * bflo(u0.w); a[7]  += c * bfhi(u0.w);
                a[8]  += c * bflo(u1.x); a[9]  += c * bfhi(u1.x);
                a[10] += c * bflo(u1.y); a[11] += c * bfhi(u1.y);
                a[12] += c * bflo(u1.z); a[13] += c * bfhi(u1.z);
                a[14] += c * bflo(u1.w); a[15] += c * bfhi(u1.w);
            }
        }
    }
#pragma unroll
    for (int k = 0; k < 16; k++) {
        a[k] += __shfl_xor(a[k], 4, 32);
        a[k] += __shfl_xor(a[k], 8, 32);
        a[k] += __shfl_xor(a[k], 16, 32);
    }

    float di = rsqrtf(1.0f + (float)deg);
    float dd = di * di;
    uint4 s0 = Aq[n * 8 + f], s1 = Aq[n * 8 + 4 + f];
    float4 bA0 = ((const float4*)bias)[2 * f];
    float4 bA1 = ((const float4*)bias)[2 * f + 1];
    float4 bB0 = ((const float4*)(bias + 32))[2 * f];
    float4 bB1 = ((const float4*)(bias + 32))[2 * f + 1];
    if (g == 0) {
        float* dst = sB + nl * 64 + 8 * f;
        dst[0] = fmaxf(di * a[0]  + dd * bflo(s0.x) + bA0.x, 0.f);
        dst[1] = fmaxf(di * a[1]  + dd * bfhi(s0.x) + bA0.y, 0.f);
        dst[2] = fmaxf(di * a[2]  + dd * bflo(s0.y) + bA0.z, 0.f);
        dst[3] = fmaxf(di * a[3]  + dd * bfhi(s0.y) + bA0.w, 0.f);
        dst[4] = fmaxf(di * a[4]  + dd * bflo(s0.z) + bA1.x, 0.f);
        dst[5] = fmaxf(di * a[5]  + dd * bfhi(s0.z) + bA1.y, 0.f);
        dst[6] = fmaxf(di * a[6]  + dd * bflo(s0.w) + bA1.z, 0.f);
        dst[7] = fmaxf(di * a[7]  + dd * bfhi(s0.w) + bA1.w, 0.f);
        float* dst2 = dst + 32;
        dst2[0] = fmaxf(di * a[8]  + dd * bflo(s1.x) + bB0.x, 0.f);
        dst2[1] = fmaxf(di * a[9]  + dd * bfhi(s1.x) + bB0.y, 0.f);
        dst2[2] = fmaxf(di * a[10] + dd * bflo(s1.y) + bB0.z, 0.f);
        dst2[3] = fmaxf(di * a[11] + dd * bfhi(s1.y) + bB0.w, 0.f);
        dst2[4] = fmaxf(di * a[12] + dd * bflo(s1.z) + bB1.x, 0.f);
        dst2[5] = fmaxf(di * a[13] + dd * bfhi(s1.z) + bB1.y, 0.f);
        dst2[6] = fmaxf(di * a[14] + dd * bflo(s1.w) + bB1.z, 0.f);
        dst2[7] = fmaxf(di * a[15] + dd * bfhi(s1.w) + bB1.w, 0.f);
    }
    __syncthreads();

    // ---- GEMM: C[32x64] = sB[32x64] @ sW[64x64], 2 rows/thread ----------
    int col = tid & 63;
    int r0  = tid >> 6;           // 0..15; rows r0 and r0+16
    float acc0 = 0.f, acc1 = 0.f;
#pragma unroll
    for (int kk = 0; kk < 64; kk++) {
        float wv = sW[kk * 64 + col];
        acc0 += sB[r0 * 64 + kk] * wv;
        acc1 += sB[(r0 + 16) * 64 + kk] * wv;
    }
    int na = blockIdx.x * 32 + r0;
    C[na * 64 + col]        = f2bf(acc0);
    C[(na + 16) * 64 + col] = f2bf(acc1);
}

// ---- layer-2 pull aggregation (normalize epilogue), merged rows ----------
__global__ void k_aggf4(const uint4* __restrict__ Cq, uint4* __restrict__ Hq,
                        const int* __restrict__ cnt,
                        const unsigned short* __restrict__ ebuf, const float* __restrict__ bias,
                        const unsigned* __restrict__ ovf, const int* __restrict__ ovf_cnt) {
    int w = (blockIdx.x * 256 + threadIdx.x) >> 6;   // wave id, 2 nodes/wave
    int lane = threadIdx.x & 63;
    int half = lane >> 5, sl = lane & 31;
    int n = w * 2 + half;
    if (n >= N_NODES) return;
    int deg = cnt[n];
    int bucketed = min(deg, CAP);
    int nb0 = min(bucketed, 32);
    int nb1 = bucketed - nb0;

    int   r0v = 0, r1v = 0;
    float d0v = 0.0f, d1v = 0.0f;
    if (sl < nb0) { r0v = (int)ebuf[n * CAP + sl];      d0v = rsqrtf(1.0f + (float)cnt[r0v]); }
    if (sl < nb1) { r1v = (int)ebuf[n * CAP + 32 + sl]; d1v = rsqrtf(1.0f + (float)cnt[r1v]); }

    int g = sl >> 2;
    int f = sl & 3;

    float a[16];
#pragma unroll
    for (int k = 0; k < 16; k++) a[k] = 0.f;
    int np0 = (nb0 + 7) >> 3;
    int np1 = (nb1 + 7) >> 3;

#pragma unroll 4
    for (int d = 0; d < np0; d++) {
        int   q = 8 * d + g;
        int   r = __shfl(r0v, q, 32);
        float c = __shfl(d0v, q, 32);
        uint4 u0 = Cq[r * 8 + f];
        uint4 u1 = Cq[r * 8 + 4 + f];
        a[0]  += c * bflo(u0.x); a[1]  += c * bfhi(u0.x);
        a[2]  += c * bflo(u0.y); a[3]  += c * bfhi(u0.y);
        a[4]  += c * bflo(u0.z); a[5]  += c * bfhi(u0.z);
        a[6]  += c * bflo(u0.w); a[7]  += c * bfhi(u0.w);
        a[8]  += c * bflo(u1.x); a[9]  += c * bfhi(u1.x);
        a[10] += c * bflo(u1.y); a[11] += c * bfhi(u1.y);
        a[12] += c * bflo(u1.z); a[13] += c * bfhi(u1.z);
        a[14] += c * bflo(u1.w); a[15] += c * bfhi(u1.w);
    }
#pragma unroll 4
    for (int d = 0; d < np1; d++) {
        int   q = 8 * d + g;
        int   r = __shfl(r1v, q, 32);
        float c = __shfl(d1v, q, 32);
        uint4 u0 = Cq[r * 8 + f];
        uint4 u1 = Cq[r * 8 + 4 + f];
        a[0]  += c * bflo(u0.x); a[1]  += c * bfhi(u0.x);
        a[2]  += c * bflo(u0.y); a[3]  += c * bfhi(u0.y);
        a[4]  += c * bflo(u0.z); a[5]  += c * bfhi(u0.z);
        a[6]  += c * bflo(u0.w); a[7]  += c * bfhi(u0.w);
        a[8]  += c * bflo(u1.x); a[9]  += c * bfhi(u1.x);
        a[10] += c * bflo(u1.y); a[11] += c * bfhi(u1.y);
        a[12] += c * bflo(u1.z); a[13] += c * bfhi(u1.z);
        a[14] += c * bflo(u1.w); a[15] += c * bfhi(u1.w);
    }
    if (deg > CAP) {
        int m = ovf_cnt[0];
        for (int k2 = 0; k2 < m; k2++) {
            unsigned p = ovf[k2];
            if ((int)(p & 0xffffu) == n && g == 0) {
                int r = (int)(p >> 16);
                float c = rsqrtf(1.0f + (float)cnt[r]);
                uint4 u0 = Cq[r * 8 + f], u1 = Cq[r * 8 + 4 + f];
                a[0]  += c * bflo(u0.x); a[1]  += c * bfhi(u0.x);
                a[2]  += c * bflo(u0.y); a[3]  += c * bfhi(u0.y);
                a[4]  += c * bflo(u0.z); a[5]  += c * bfhi(u0.z);
                a[6]  += c * bflo(u0.w); a[7]  += c * bfhi(u0.w);
                a[8]  += c * bflo(u1.x); a[9]  += c * bfhi(u1.x);
                a[10] += c * bflo(u1.y); a[11] += c * bfhi(u1.y);
                a[12] += c * bflo(u1.z); a[13] += c * bfhi(u1.z);
                a[14] += c * bflo(u1.w); a[15] += c * bfhi(u1.w);
            }
        }
    }
#pragma unroll
    for (int k = 0; k < 16; k++) {
        a[k] += __shfl_xor(a[k], 4, 32);
        a[k] += __shfl_xor(a[k], 8, 32);
        a[k] += __shfl_xor(a[k], 16, 32);
    }

    float di = rsqrtf(1.0f + (float)deg);
    float dd = di * di;
    uint4 s0 = Cq[n * 8 + f], s1 = Cq[n * 8 + 4 + f];
    float4 bA0 = ((const float4*)bias)[2 * f];
    float4 bA1 = ((const float4*)bias)[2 * f + 1];
    float4 bB0 = ((const float4*)(bias + 32))[2 * f];
    float4 bB1 = ((const float4*)(bias + 32))[2 * f + 1];
    float v[16];
    v[0]  = di * a[0]  + dd * bflo(s0.x) + bA0.x;
    v[1]  = di * a[1]  + dd * bfhi(s0.x) + bA0.y;
    v[2]  = di * a[2]  + dd * bflo(s0.y) + bA0.z;
    v[3]  = di * a[3]  + dd * bfhi(s0.y) + bA0.w;
    v[4]  = di * a[4]  + dd * bflo(s0.z) + bA1.x;
    v[5]  = di * a[5]  + dd * bfhi(s0.z) + bA1.y;
    v[6]  = di * a[6]  + dd * bflo(s0.w) + bA1.z;
    v[7]  = di * a[7]  + dd * bfhi(s0.w) + bA1.w;
    v[8]  = di * a[8]  + dd * bflo(s1.x) + bB0.x;
    v[9]  = di * a[9]  + dd * bfhi(s1.x) + bB0.y;
    v[10] = di * a[10] + dd * bflo(s1.y) + bB0.z;
    v[11] = di * a[11] + dd * bfhi(s1.y) + bB0.w;
    v[12] = di * a[12] + dd * bflo(s1.z) + bB1.x;
    v[13] = di * a[13] + dd * bfhi(s1.z) + bB1.y;
    v[14] = di * a[14] + dd * bflo(s1.w) + bB1.z;
    v[15] = di * a[15] + dd * bfhi(s1.w) + bB1.w;

    float s = 0.f;
#pragma unroll
    for (int k = 0; k < 16; k++) s += v[k] * v[k];
    s += __shfl_xor(s, 1, 32);
    s += __shfl_xor(s, 2, 32);
    float inv = 1.0f / fmaxf(sqrtf(s), 1e-12f);
#pragma unroll
    for (int k = 0; k < 16; k++) v[k] *= inv;
    if (g == 0) {
        Hq[n * 8 + f]     = make_uint4(pack2(v[0], v[1]),  pack2(v[2], v[3]),
                                       pack2(v[4], v[5]),  pack2(v[6], v[7]));
        Hq[n * 8 + 4 + f] = make_uint4(pack2(v[8], v[9]),  pack2(v[10], v[11]),
                                       pack2(v[12], v[13]), pack2(v[14], v[15]));
    }
}

// ---- fused edge dot + finalize + symmetrize: 1 thread/edge ---------------
// 16 uint4 loads per thread (two contiguous 128 B rows) - max MLP, no shfl.
__global__ void k_dotsym(const uint4* __restrict__ Hq,
                         const float* __restrict__ s_d, const int* __restrict__ j_idx,
                         const unsigned char* __restrict__ revb,
                         float* __restrict__ outS) {   // d_out + 2E, holds vals_s [2E]
    int e = blockIdx.x * 256 + threadIdx.x;   // NE threads
    int i = e / KNN;
    int j = j_idx[e];
    const uint4* Hi = Hq + i * 8;
    const uint4* Hj = Hq + j * 8;
    float s = 0.f;
#pragma unroll
    for (int k = 0; k < 8; k++) s += dot8(Hi[k], Hj[k]);
    float base = OMEGA * fmaxf(s, 0.0f);
    int rt = revb[e];
    float vv, v2;
    if (rt != 255) {                     // reverse edge exists (rare)
        int rev = j * KNN + rt;
        vv = base + 0.5f * (1.0f - OMEGA) * (s_d[e] + s_d[rev]);
        v2 = 0.0f;
    } else {
        vv = base + (1.0f - OMEGA) * s_d[e];
        v2 = vv;
    }
    outS[e] = vv;
    outS[NE + e] = v2;
}

// ---- binned in-edge accumulation + fused dinv2 ---------------------------
__global__ void k_jagg(const unsigned* __restrict__ jbbuf, const int* __restrict__ jbcnt,
                       const float* __restrict__ outS, float* __restrict__ dinv2,
                       const unsigned* __restrict__ jovf, const int* __restrict__ jovf_cnt,
                       const int* __restrict__ j_idx) {
    __shared__ float ld[512];
    int b = blockIdx.x;
    int tid = threadIdx.x;                   // 1024 threads
    if (tid < 512) ld[tid] = 0.0f;
    __syncthreads();
    const float* outSv2 = outS + NE;
    int n = min(jbcnt[b], JBCAP);
    for (int idx = tid; idx < n; idx += 1024) {
        unsigned p = jbbuf[b * JBCAP + idx];
        atomicAdd(&ld[p >> 20], outSv2[p & 0xFFFFFu]);
    }
    int m = jovf_cnt[0];                     // learner bin overflow (normally 0)
    for (int t2 = tid; t2 < m; t2 += 1024) {
        int e = (int)(jovf[t2] & 0xFFFFFu);
        int j = j_idx[e];
        if ((j >> 9) == b) atomicAdd(&ld[j & 511], outSv2[e]);
    }
    __syncthreads();
    if (tid < 512) {
        int node = b * 512 + tid;
        if (node < N_NODES) {
            float d = ld[tid];
            const float* pp = outS + node * KNN;
#pragma unroll
            for (int qq = 0; qq < KNN; qq++) d += pp[qq];
            dinv2[node] = (d > 0.0f) ? rsqrtf(fmaxf(d, 1e-12f)) : 0.0f;
        }
    }
}

// ---- final normalization: vals_norm = dinv2[r] * vals_s * dinv2[c] -------
__global__ void k_norm(const float* __restrict__ outS, const float* __restrict__ dinv2,
                       const int* __restrict__ j_idx, float* __restrict__ out) {
    int t = blockIdx.x * 256 + threadIdx.x;   // 2*NE threads
    int r, c;
    if (t < NE) { r = t / KNN; c = j_idx[t]; }
    else        { int e = t - NE; r = j_idx[e]; c = e / KNN; }
    out[t] = dinv2[r] * outS[t] * dinv2[c];
}

extern "C" void kernel_launch(void* const* d_in, const int* in_sizes, int n_in,
                              void* d_out, int out_size, void* d_ws, size_t ws_size,
                              hipStream_t stream) {
    const float* features = (const float*)d_in[0];
    const float* W1       = (const float*)d_in[1];
    const float* b1       = (const float*)d_in[2];
    const float* W2       = (const float*)d_in[3];
    const float* b2       = (const float*)d_in[4];
    const float* s_d      = (const float*)d_in[5];
    const int*   adj_row  = (const int*)d_in[6];
    const int*   adj_col  = (const int*)d_in[7];
    const int*   j_idx    = (const int*)d_in[9];
    float* out = (float*)d_out;

    const int N64 = N_NODES * 64;
    // Workspace layout (zero region first, all offsets 16B-aligned):
    // [cnt N][ovfcnts 16][bcnt 80][jbcnt 80]  <- memset 0
    // [dinv2 N][A N64 us][C N64 us][H N64 us]
    // [ebuf N*CAP us][ovf NE u][revb NE uc][bbuf][jbbuf][ovf2 NE u][jovf NE u]
    int*   cnt     = (int*)d_ws;
    int*   ovfcnts = cnt + N_NODES;          // [0]=CAP ovf, [4]=adj bin ovf, [8]=learner bin ovf
    int*   bcnt    = ovfcnts + 16;
    int*   jbcnt   = bcnt + NBUCK;
    float* dinv2   = (float*)(jbcnt + NBUCK);
    unsigned short* A   = (unsigned short*)(dinv2 + N_NODES);
    unsigned short* C   = A + N64;
    unsigned short* H   = C + N64;
    unsigned short* ebuf = H + N64;              // N*CAP ushorts
    unsigned* ovf    = (unsigned*)(ebuf + N_NODES * CAP);
    unsigned char* revb = (unsigned char*)(ovf + NE);
    unsigned* bbuf   = (unsigned*)(revb + NE);   // NBUCK*BCAP
    unsigned* jbbuf  = bbuf + NBUCK * BCAP;      // NBUCK*JBCAP
    unsigned* ovf2   = jbbuf + NBUCK * JBCAP;    // NE
    unsigned* jovf   = ovf2 + NE;                // NE

    // Re-init (ws is poisoned 0xAA before every call)
    size_t zero_bytes = (size_t)(N_NODES + 16 + 2 * NBUCK) * 4;
    hipMemsetAsync(cnt, 0, zero_bytes, stream);

    // Mega front end: gemm1 + bin(both sets) + reverse-edge scan (1 thr/edge)
    const int GB = N_NODES / 32;                          // 1250
    const int NBA = (NE + 256 * EPT - 1) / (256 * EPT);   // 469
    const int RB = NE / 256;                              // 3750
    k_mega1<<<GB + 2 * NBA + RB, 256, 0, stream>>>(
        features, W1, A, adj_row, adj_col, j_idx,
        bcnt, bbuf, ovf2, ovfcnts + 4, jbcnt, jbbuf, jovf, ovfcnts + 8, revb);

    // Per-bucket scatter (LDS slots, no global atomics) -> ebuf + cnt
    k_scatter3<<<NBUCK, 1024, 0, stream>>>(bbuf, bcnt, cnt, ebuf,
                                           ovf, ovfcnts, ovf2, ovfcnts + 4);

    // Fused layer-1: agg(A)+ReLU -> LDS -> xW2 -> C  (32 nodes/block)
    k_aggemm1<<<N_NODES / 32, 1024, 0, stream>>>(
        (const uint4*)A, W2, C, cnt, ebuf, b1, ovf, ovfcnts);

    // Layer-2 aggregate + normalize -> H  (2 nodes/wave, 32 lanes/node)
    k_aggf4<<<(N_NODES / 2 * 64 + 255) / 256, 256, 0, stream>>>(
        (const uint4*)C, (uint4*)H, cnt, ebuf, b2, ovf, ovfcnts);

    // Fused edge scores + symmetrize (atomic-free, 1 thread/edge, 16 loads)
    float* outS = out + 2 * NE;
    k_dotsym<<<NE / 256, 256, 0, stream>>>(
        (const uint4*)H, s_d, j_idx, revb, outS);

    // Binned in-edge accumulation + dinv2, then final normalize
    k_jagg<<<NBUCK, 1024, 0, stream>>>(jbbuf, jbcnt, outS, dinv2, jovf, ovfcnts + 8, j_idx);
    k_norm<<<2 * NE / 256, 256, 0, stream>>>(outS, dinv2, j_idx, out);
}

// Round 17
// 235.392 us; speedup vs baseline: 1.0356x; 1.0356x over previous
//
#include <hip/hip_runtime.h>

// Problem constants (match reference)
#define N_NODES 40000
#define ISIZE   64
#define KNN     24
#define NE      (N_NODES * KNN)      // 960000 edges (= E_ADJ as well)
#define OMEGA   0.9f
#define CAP     64                   // per-node bucket capacity (max deg ~46)
#define NBUCK   80                   // buckets of 512 nodes (idx>>9)
#define BCAP    16384                // adj edges per bucket capacity (mean 12288)
#define JBCAP   16384                // learner edges per bucket capacity
#define EPT     8                    // edges per thread in bin pass

// ---- bf16 helpers (storage-only precision; all math in fp32) -------------
__device__ __forceinline__ float bf2f(unsigned short s) {
    return __uint_as_float(((unsigned)s) << 16);
}
__device__ __forceinline__ unsigned short f2bf(float f) {  // round-nearest-even
    unsigned u = __float_as_uint(f);
    u += 0x7fffu + ((u >> 16) & 1u);
    return (unsigned short)(u >> 16);
}
__device__ __forceinline__ float bflo(unsigned u) { return __uint_as_float(u << 16); }
__device__ __forceinline__ float bfhi(unsigned u) { return __uint_as_float(u & 0xffff0000u); }
__device__ __forceinline__ unsigned pack2(float lo, float hi) {
    return (unsigned)f2bf(lo) | ((unsigned)f2bf(hi) << 16);
}
__device__ __forceinline__ float dot8(uint4 a, uint4 b) {
    return bflo(a.x) * bflo(b.x) + bfhi(a.x) * bfhi(b.x)
         + bflo(a.y) * bflo(b.y) + bfhi(a.y) * bfhi(b.y)
         + bflo(a.z) * bflo(b.z) + bfhi(a.z) * bfhi(b.z)
         + bflo(a.w) * bflo(b.w) + bfhi(a.w) * bfhi(b.w);
}

// ---- mega front end: gemm layer1 | bin both edge sets | reverse scan -----
// Node feature rows are stored MERGED: 64 bf16 = 128 B per row (uint4 x 8).
__global__ void k_mega1(const float* __restrict__ X, const float* __restrict__ W,
                        unsigned short* __restrict__ Y,
                        const int* __restrict__ row, const int* __restrict__ col,
                        const int* __restrict__ j_idx,
                        int* __restrict__ bcnt, unsigned* __restrict__ bbuf,
                        unsigned* __restrict__ ovf2, int* __restrict__ ovf2_cnt,
                        int* __restrict__ jbcnt, unsigned* __restrict__ jbbuf,
                        unsigned* __restrict__ jovf, int* __restrict__ jovf_cnt,
                        unsigned char* __restrict__ revb) {
    __shared__ float sW[64 * 64];    // gemm: W tile | bin: lcnt/lbase overlay
    __shared__ float sX[32 * 64];
    const int GB  = N_NODES / 32;                          // 1250 gemm blocks
    const int NBA = (NE + 256 * EPT - 1) / (256 * EPT);    // 469 bin blocks per set
    int bx = blockIdx.x;
    int tid = threadIdx.x;
    if (bx < GB) {
        // ---- GEMM layer 1: rows bx*32.., merged bf16 output ----
        int row0 = bx * 32;
        for (int t = tid; t < 1024; t += 256)
            ((float4*)sW)[t] = ((const float4*)W)[t];
        for (int t = tid; t < 512; t += 256)
            ((float4*)sX)[t] = ((const float4*)(X + row0 * 64))[t];
        __syncthreads();
        int cc = tid & 63;
        int rl = tid >> 6;
        for (int r = rl; r < 32; r += 4) {
            float acc = 0.0f;
#pragma unroll
            for (int kk = 0; kk < 64; kk++) acc += sX[r * 64 + kk] * sW[kk * 64 + cc];
            Y[(row0 + r) * 64 + cc] = f2bf(acc);
        }
    } else if (bx < GB + 2 * NBA) {
        // ---- bin edges: adj by col (r<<16|c), learner by j ((j&511)<<20|e)
        int* lcnt  = (int*)sW;
        int* lbase = lcnt + NBUCK;
        int blk = bx - GB;
        bool adj = blk < NBA;
        if (!adj) blk -= NBA;
        for (int b = tid; b < NBUCK; b += 256) lcnt[b] = 0;
        __syncthreads();
        int e0 = blk * (256 * EPT);
        int myslot[EPT]; int myb[EPT]; unsigned myp[EPT];
        for (int k = 0; k < EPT; k++) {
            int e = e0 + k * 256 + tid;
            if (e < NE) {
                int b; unsigned p;
                if (adj) { int r = row[e], c = col[e]; b = c >> 9; p = ((unsigned)r << 16) | (unsigned)c; }
                else     { int j = j_idx[e];           b = j >> 9; p = ((unsigned)(j & 511) << 20) | (unsigned)e; }
                myb[k] = b; myp[k] = p;
                myslot[k] = atomicAdd(&lcnt[b], 1);
            } else myb[k] = -1;
        }
        __syncthreads();
        int* gcnt = adj ? bcnt : jbcnt;
        for (int b = tid; b < NBUCK; b += 256)
            lbase[b] = (lcnt[b] > 0) ? atomicAdd(&gcnt[b], lcnt[b]) : 0;
        __syncthreads();
        unsigned* gbuf = adj ? bbuf : jbbuf;
        unsigned* govf = adj ? ovf2 : jovf;
        int* gocnt = adj ? ovf2_cnt : jovf_cnt;
        for (int k = 0; k < EPT; k++) {
            if (myb[k] < 0) continue;
            int pos = lbase[myb[k]] + myslot[k];
            if (pos < BCAP) gbuf[myb[k] * BCAP + pos] = myp[k];
            else { int p = atomicAdd(gocnt, 1); govf[p] = myp[k]; }
        }
    } else {
        // ---- reverse-edge match: 1 thread/edge, 6 x uint4 over j's slice -
        int e = (bx - GB - 2 * NBA) * 256 + tid;   // NE threads
        int i = e / KNN;
        int j = j_idx[e];
        const uint4* jj4 = (const uint4*)(j_idx + j * KNN);  // 96B rows: 16B-aligned
        int rt = 255;
#pragma unroll
        for (int k = 5; k >= 0; k--) {             // descending so min index wins
            uint4 u = jj4[k];
            if ((int)u.w == i) rt = 4 * k + 3;
            if ((int)u.z == i) rt = 4 * k + 2;
            if ((int)u.y == i) rt = 4 * k + 1;
            if ((int)u.x == i) rt = 4 * k + 0;
        }
        revb[e] = (unsigned char)rt;
    }
}

// ---- per-bucket scatter: LDS slot assignment, NO global atomics ----------
__global__ void k_scatter3(const unsigned* __restrict__ bbuf, const int* __restrict__ bcnt,
                           int* __restrict__ cnt, unsigned short* __restrict__ ebuf,
                           unsigned* __restrict__ ovf, int* __restrict__ ovf_cnt,
                           const unsigned* __restrict__ ovf2, const int* __restrict__ ovf2_cnt) {
    __shared__ int lcnt2[512];
    int b = blockIdx.x;
    int tid = threadIdx.x;                   // 1024 threads
    if (tid < 512) lcnt2[tid] = 0;
    __syncthreads();
    int n = min(bcnt[b], BCAP);
    for (int idx = tid; idx < n; idx += 1024) {
        unsigned p = bbuf[b * BCAP + idx];
        int c = (int)(p & 0xffffu), r = (int)(p >> 16);
        int slot = atomicAdd(&lcnt2[c & 511], 1);
        if (slot < CAP) ebuf[c * CAP + slot] = (unsigned short)r;
        else { int q = atomicAdd(ovf_cnt, 1); ovf[q] = p; }
    }
    int m = ovf2_cnt[0];                     // adj bin overflow (normally 0)
    for (int idx = tid; idx < m; idx += 1024) {
        unsigned p = ovf2[idx];
        int c = (int)(p & 0xffffu), r = (int)(p >> 16);
        if ((c >> 9) != b) continue;
        int slot = atomicAdd(&lcnt2[c & 511], 1);
        if (slot < CAP) ebuf[c * CAP + slot] = (unsigned short)r;
        else { int q = atomicAdd(ovf_cnt, 1); ovf[q] = p; }
    }
    __syncthreads();
    if (tid < 512) {
        int node = b * 512 + tid;
        if (node < N_NODES) cnt[node] = lcnt2[tid];   // full degree (incl. >CAP)
    }
}

// ---- fused layer-1: pull-agg + self + bias + ReLU, then xW2 GEMM ---------
// 1024 threads = 16 waves = 32 nodes per block (2 nodes/wave).
// Merged 128B rows: per gathered row, 2 ADJACENT uint4 loads (one L2 line).
__global__ void __launch_bounds__(1024, 1)
k_aggemm1(const uint4* __restrict__ Aq, const float* __restrict__ W2,
          unsigned short* __restrict__ C,
          const int* __restrict__ cnt,
          const unsigned short* __restrict__ ebuf, const float* __restrict__ bias,
          const unsigned* __restrict__ ovf, const int* __restrict__ ovf_cnt) {
    __shared__ float sW[64 * 64];     // 16 KB
    __shared__ float sB[32 * 64];     // 8 KB
    int tid  = threadIdx.x;
    int lane = tid & 63;
    int half = lane >> 5, sl = lane & 31;
    int nl = (tid >> 6) * 2 + half;   // local node 0..31
    int n  = blockIdx.x * 32 + nl;    // exact fit: 1250*32 == N_NODES

    // stage W2 (coalesced; no dependency until gemm phase)
    ((float4*)sW)[tid] = ((const float4*)W2)[tid];

    int deg = cnt[n];
    int bucketed = min(deg, CAP);
    int nb0 = min(bucketed, 32);
    int nb1 = bucketed - nb0;

    int   r0v = 0, r1v = 0;
    float d0v = 0.0f, d1v = 0.0f;
    if (sl < nb0) { r0v = (int)ebuf[n * CAP + sl];      d0v = rsqrtf(1.0f + (float)cnt[r0v]); }
    if (sl < nb1) { r1v = (int)ebuf[n * CAP + 32 + sl]; d1v = rsqrtf(1.0f + (float)cnt[r1v]); }

    int g = sl >> 2;          // row subgroup 0..7
    int f = sl & 3;           // uint4 quarter

    float a[16];
#pragma unroll
    for (int k = 0; k < 16; k++) a[k] = 0.f;
    int np0 = (nb0 + 7) >> 3;
    int np1 = (nb1 + 7) >> 3;

#pragma unroll 4
    for (int d = 0; d < np0; d++) {
        int   q = 8 * d + g;
        int   r = __shfl(r0v, q, 32);
        float c = __shfl(d0v, q, 32);
        uint4 u0 = Aq[r * 8 + f];
        uint4 u1 = Aq[r * 8 + 4 + f];
        a[0]  += c * bflo(u0.x); a[1]  += c * bfhi(u0.x);
        a[2]  += c * bflo(u0.y); a[3]  += c * bfhi(u0.y);
        a[4]  += c * bflo(u0.z); a[5]  += c * bfhi(u0.z);
        a[6]  += c * bflo(u0.w); a[7]  += c * bfhi(u0.w);
        a[8]  += c * bflo(u1.x); a[9]  += c * bfhi(u1.x);
        a[10] += c * bflo(u1.y); a[11] += c * bfhi(u1.y);
        a[12] += c * bflo(u1.z); a[13] += c * bfhi(u1.z);
        a[14] += c * bflo(u1.w); a[15] += c * bfhi(u1.w);
    }
#pragma unroll 4
    for (int d = 0; d < np1; d++) {
        int   q = 8 * d + g;
        int   r = __shfl(r1v, q, 32);
        float c = __shfl(d1v, q, 32);
        uint4 u0 = Aq[r * 8 + f];
        uint4 u1 = Aq[r * 8 + 4 + f];
        a[0]  += c * bflo(u0.x); a[1]  += c * bfhi(u0.x);
        a[2]  += c * bflo(u0.y); a[3]  += c * bfhi(u0.y);
        a[4]  += c * bflo(u0.z); a[5]  += c * bfhi(u0.z);
        a[6]  += c * bflo(u0.w); a[7]  += c * bfhi(u0.w);
        a[8]  += c * bflo(u1.x); a[9]  += c * bfhi(u1.x);
        a[10] += c * bflo(u1.y); a[11] += c * bfhi(u1.y);
        a[12] += c * bflo(u1.z); a[13] += c * bfhi(u1.z);
        a[14] += c * bflo(u1.w); a[15] += c * bfhi(u1.w);
    }
    if (deg > CAP) {                         // CAP overflow (normally none)
        int m = ovf_cnt[0];
        for (int k2 = 0; k2 < m; k2++) {
            unsigned p = ovf[k2];
            if ((int)(p & 0xffffu) == n && g == 0) {
                int r = (int)(p >> 16);
                float c = rsqrtf(1.0f + (float)cnt[r]);
                uint4 u0 = Aq[r * 8 + f], u1 = Aq[r * 8 + 4 + f];
                a[0]  += c * bflo(u0.x); a[1]  += c * bfhi(u0.x);
                a[2]  += c * bflo(u0.y); a[3]  += c * bfhi(u0.y);
                a[4]  += c * bflo(u0.z); a[5]  += c * bfhi(u0.z);
                a[6]  += c * bflo(u0.w); a[7]  += c * bfhi(u0.w);
                a[8]  += c * bflo(u1.x); a[9]  += c * bfhi(u1.x);
                a[10] += c * bflo(u1.y); a[11] += c * bfhi(u1.y);
                a[12] += c * bflo(u1.z); a[13] += c * bfhi(u1.z);
                a[14] += c * bflo(u1.w); a[15] += c * bfhi(u1.w);
            }
        }
    }
#pragma unroll
    for (int k = 0; k < 16; k++) {
        a[k] += __shfl_xor(a[k], 4, 32);
        a[k] += __shfl_xor(a[k], 8, 32);
        a[k] += __shfl_xor(a[k], 16, 32);
    }

    float di = rsqrtf(1.0f + (float)deg);
    float dd = di * di;
    uint4 s0 = Aq[n * 8 + f], s1 = Aq[n * 8 + 4 + f];
    float4 bA0 = ((const float4*)bias)[2 * f];
    float4 bA1 = ((const float4*)bias)[2 * f + 1];
    float4 bB0 = ((const float4*)(bias + 32))[2 * f];
    float4 bB1 = ((const float4*)(bias + 32))[2 * f + 1];
    if (g == 0) {
        float* dst = sB + nl * 64 + 8 * f;
        dst[0] = fmaxf(di * a[0]  + dd * bflo(s0.x) + bA0.x, 0.f);
        dst[1] = fmaxf(di * a[1]  + dd * bfhi(s0.x) + bA0.y, 0.f);
        dst[2] = fmaxf(di * a[2]  + dd * bflo(s0.y) + bA0.z, 0.f);
        dst[3] = fmaxf(di * a[3]  + dd * bfhi(s0.y) + bA0.w, 0.f);
        dst[4] = fmaxf(di * a[4]  + dd * bflo(s0.z) + bA1.x, 0.f);
        dst[5] = fmaxf(di * a[5]  + dd * bfhi(s0.z) + bA1.y, 0.f);
        dst[6] = fmaxf(di * a[6]  + dd * bflo(s0.w) + bA1.z, 0.f);
        dst[7] = fmaxf(di * a[7]  + dd * bfhi(s0.w) + bA1.w, 0.f);
        float* dst2 = dst + 32;
        dst2[0] = fmaxf(di * a[8]  + dd * bflo(s1.x) + bB0.x, 0.f);
        dst2[1] = fmaxf(di * a[9]  + dd * bfhi(s1.x) + bB0.y, 0.f);
        dst2[2] = fmaxf(di * a[10] + dd * bflo(s1.y) + bB0.z, 0.f);
        dst2[3] = fmaxf(di * a[11] + dd * bfhi(s1.y) + bB0.w, 0.f);
        dst2[4] = fmaxf(di * a[12] + dd * bflo(s1.z) + bB1.x, 0.f);
        dst2[5] = fmaxf(di * a[13] + dd * bfhi(s1.z) + bB1.y, 0.f);
        dst2[6] = fmaxf(di * a[14] + dd * bflo(s1.w) + bB1.z, 0.f);
        dst2[7] = fmaxf(di * a[15] + dd * bfhi(s1.w) + bB1.w, 0.f);
    }
    __syncthreads();

    // ---- GEMM: C[32x64] = sB[32x64] @ sW[64x64], 2 rows/thread ----------
    int col = tid & 63;
    int r0  = tid >> 6;           // 0..15; rows r0 and r0+16
    float acc0 = 0.f, acc1 = 0.f;
#pragma unroll
    for (int kk = 0; kk < 64; kk++) {
        float wv = sW[kk * 64 + col];
        acc0 += sB[r0 * 64 + kk] * wv;
        acc1 += sB[(r0 + 16) * 64 + kk] * wv;
    }
    int na = blockIdx.x * 32 + r0;
    C[na * 64 + col]        = f2bf(acc0);
    C[(na + 16) * 64 + col] = f2bf(acc1);
}

// ---- layer-2 pull aggregation (normalize epilogue), merged rows ----------
__global__ void k_aggf4(const uint4* __restrict__ Cq, uint4* __restrict__ Hq,
                        const int* __restrict__ cnt,
                        const unsigned short* __restrict__ ebuf, const float* __restrict__ bias,
                        const unsigned* __restrict__ ovf, const int* __restrict__ ovf_cnt) {
    int w = (blockIdx.x * 256 + threadIdx.x) >> 6;   // wave id, 2 nodes/wave
    int lane = threadIdx.x & 63;
    int half = lane >> 5, sl = lane & 31;
    int n = w * 2 + half;
    if (n >= N_NODES) return;
    int deg = cnt[n];
    int bucketed = min(deg, CAP);
    int nb0 = min(bucketed, 32);
    int nb1 = bucketed - nb0;

    int   r0v = 0, r1v = 0;
    float d0v = 0.0f, d1v = 0.0f;
    if (sl < nb0) { r0v = (int)ebuf[n * CAP + sl];      d0v = rsqrtf(1.0f + (float)cnt[r0v]); }
    if (sl < nb1) { r1v = (int)ebuf[n * CAP + 32 + sl]; d1v = rsqrtf(1.0f + (float)cnt[r1v]); }

    int g = sl >> 2;
    int f = sl & 3;

    float a[16];
#pragma unroll
    for (int k = 0; k < 16; k++) a[k] = 0.f;
    int np0 = (nb0 + 7) >> 3;
    int np1 = (nb1 + 7) >> 3;

#pragma unroll 4
    for (int d = 0; d < np0; d++) {
        int   q = 8 * d + g;
        int   r = __shfl(r0v, q, 32);
        float c = __shfl(d0v, q, 32);
        uint4 u0 = Cq[r * 8 + f];
        uint4 u1 = Cq[r * 8 + 4 + f];
        a[0]  += c * bflo(u0.x); a[1]  += c * bfhi(u0.x);
        a[2]  += c * bflo(u0.y); a[3]  += c * bfhi(u0.y);
        a[4]  += c * bflo(u0.z); a[5]  += c * bfhi(u0.z);
        a[6]  += c * bflo(u0.w); a[7]  += c * bfhi(u0.w);
        a[8]  += c * bflo(u1.x); a[9]  += c * bfhi(u1.x);
        a[10] += c * bflo(u1.y); a[11] += c * bfhi(u1.y);
        a[12] += c * bflo(u1.z); a[13] += c * bfhi(u1.z);
        a[14] += c * bflo(u1.w); a[15] += c * bfhi(u1.w);
    }
#pragma unroll 4
    for (int d = 0; d < np1; d++) {
        int   q = 8 * d + g;
        int   r = __shfl(r1v, q, 32);
        float c = __shfl(d1v, q, 32);
        uint4 u0 = Cq[r * 8 + f];
        uint4 u1 = Cq[r * 8 + 4 + f];
        a[0]  += c * bflo(u0.x); a[1]  += c * bfhi(u0.x);
        a[2]  += c * bflo(u0.y); a[3]  += c * bfhi(u0.y);
        a[4]  += c * bflo(u0.z); a[5]  += c * bfhi(u0.z);
        a[6]  += c * bflo(u0.w); a[7]  += c * bfhi(u0.w);
        a[8]  += c * bflo(u1.x); a[9]  += c * bfhi(u1.x);
        a[10] += c * bflo(u1.y); a[11] += c * bfhi(u1.y);
        a[12] += c * bflo(u1.z); a[13] += c * bfhi(u1.z);
        a[14] += c * bflo(u1.w); a[15] += c * bfhi(u1.w);
    }
    if (deg > CAP) {
        int m = ovf_cnt[0];
        for (int k2 = 0; k2 < m; k2++) {
            unsigned p = ovf[k2];
            if ((int)(p & 0xffffu) == n && g == 0) {
                int r = (int)(p >> 16);
                float c = rsqrtf(1.0f + (float)cnt[r]);
                uint4 u0 = Cq[r * 8 + f], u1 = Cq[r * 8 + 4 + f];
                a[0]  += c * bflo(u0.x); a[1]  += c * bfhi(u0.x);
                a[2]  += c * bflo(u0.y); a[3]  += c * bfhi(u0.y);
                a[4]  += c * bflo(u0.z); a[5]  += c * bfhi(u0.z);
                a[6]  += c * bflo(u0.w); a[7]  += c * bfhi(u0.w);
                a[8]  += c * bflo(u1.x); a[9]  += c * bfhi(u1.x);
                a[10] += c * bflo(u1.y); a[11] += c * bfhi(u1.y);
                a[12] += c * bflo(u1.z); a[13] += c * bfhi(u1.z);
                a[14] += c * bflo(u1.w); a[15] += c * bfhi(u1.w);
            }
        }
    }
#pragma unroll
    for (int k = 0; k < 16; k++) {
        a[k] += __shfl_xor(a[k], 4, 32);
        a[k] += __shfl_xor(a[k], 8, 32);
        a[k] += __shfl_xor(a[k], 16, 32);
    }

    float di = rsqrtf(1.0f + (float)deg);
    float dd = di * di;
    uint4 s0 = Cq[n * 8 + f], s1 = Cq[n * 8 + 4 + f];
    float4 bA0 = ((const float4*)bias)[2 * f];
    float4 bA1 = ((const float4*)bias)[2 * f + 1];
    float4 bB0 = ((const float4*)(bias + 32))[2 * f];
    float4 bB1 = ((const float4*)(bias + 32))[2 * f + 1];
    float v[16];
    v[0]  = di * a[0]  + dd * bflo(s0.x) + bA0.x;
    v[1]  = di * a[1]  + dd * bfhi(s0.x) + bA0.y;
    v[2]  = di * a[2]  + dd * bflo(s0.y) + bA0.z;
    v[3]  = di * a[3]  + dd * bfhi(s0.y) + bA0.w;
    v[4]  = di * a[4]  + dd * bflo(s0.z) + bA1.x;
    v[5]  = di * a[5]  + dd * bfhi(s0.z) + bA1.y;
    v[6]  = di * a[6]  + dd * bflo(s0.w) + bA1.z;
    v[7]  = di * a[7]  + dd * bfhi(s0.w) + bA1.w;
    v[8]  = di * a[8]  + dd * bflo(s1.x) + bB0.x;
    v[9]  = di * a[9]  + dd * bfhi(s1.x) + bB0.y;
    v[10] = di * a[10] + dd * bflo(s1.y) + bB0.z;
    v[11] = di * a[11] + dd * bfhi(s1.y) + bB0.w;
    v[12] = di * a[12] + dd * bflo(s1.z) + bB1.x;
    v[13] = di * a[13] + dd * bfhi(s1.z) + bB1.y;
    v[14] = di * a[14] + dd * bflo(s1.w) + bB1.z;
    v[15] = di * a[15] + dd * bfhi(s1.w) + bB1.w;

    float s = 0.f;
#pragma unroll
    for (int k = 0; k < 16; k++) s += v[k] * v[k];
    s += __shfl_xor(s, 1, 32);
    s += __shfl_xor(s, 2, 32);
    float inv = 1.0f / fmaxf(sqrtf(s), 1e-12f);
#pragma unroll
    for (int k = 0; k < 16; k++) v[k] *= inv;
    if (g == 0) {
        Hq[n * 8 + f]     = make_uint4(pack2(v[0], v[1]),  pack2(v[2], v[3]),
                                       pack2(v[4], v[5]),  pack2(v[6], v[7]));
        Hq[n * 8 + 4 + f] = make_uint4(pack2(v[8], v[9]),  pack2(v[10], v[11]),
                                       pack2(v[12], v[13]), pack2(v[14], v[15]));
    }
}

// ---- fused edge dot + finalize + symmetrize: 2 lanes/edge ----------------
// Lane f in {0,1} loads 64 B (4 consecutive uint4) of i's row and of j's row
// -> 8 outstanding loads/lane, lane pairs cover each 128 B row contiguously.
__global__ void k_dotsym(const uint4* __restrict__ Hq,
                         const float* __restrict__ s_d, const int* __restrict__ j_idx,
                         const unsigned char* __restrict__ revb,
                         float* __restrict__ outS) {   // d_out + 2E, holds vals_s [2E]
    int t = blockIdx.x * 256 + threadIdx.x;   // NE*2 threads
    int e = t >> 1;
    int f = t & 1;
    int i = e / KNN;
    int j = j_idx[e];
    const uint4* Hi = Hq + i * 8 + 4 * f;
    const uint4* Hj = Hq + j * 8 + 4 * f;
    uint4 a0 = Hi[0], a1 = Hi[1], a2 = Hi[2], a3 = Hi[3];
    uint4 b0 = Hj[0], b1 = Hj[1], b2 = Hj[2], b3 = Hj[3];
    float s = dot8(a0, b0) + dot8(a1, b1) + dot8(a2, b2) + dot8(a3, b3);
    s += __shfl_xor(s, 1);
    if (f == 0) {
        float base = OMEGA * fmaxf(s, 0.0f);
        int rt = revb[e];
        float vv, v2;
        if (rt != 255) {                     // reverse edge exists (rare)
            int rev = j * KNN + rt;
            vv = base + 0.5f * (1.0f - OMEGA) * (s_d[e] + s_d[rev]);
            v2 = 0.0f;
        } else {
            vv = base + (1.0f - OMEGA) * s_d[e];
            v2 = vv;
        }
        outS[e] = vv;
        outS[NE + e] = v2;
    }
}

// ---- binned in-edge accumulation + fused dinv2 ---------------------------
__global__ void k_jagg(const unsigned* __restrict__ jbbuf, const int* __restrict__ jbcnt,
                       const float* __restrict__ outS, float* __restrict__ dinv2,
                       const unsigned* __restrict__ jovf, const int* __restrict__ jovf_cnt,
                       const int* __restrict__ j_idx) {
    __shared__ float ld[512];
    int b = blockIdx.x;
    int tid = threadIdx.x;                   // 1024 threads
    if (tid < 512) ld[tid] = 0.0f;
    __syncthreads();
    const float* outSv2 = outS + NE;
    int n = min(jbcnt[b], JBCAP);
    for (int idx = tid; idx < n; idx += 1024) {
        unsigned p = jbbuf[b * JBCAP + idx];
        atomicAdd(&ld[p >> 20], outSv2[p & 0xFFFFFu]);
    }
    int m = jovf_cnt[0];                     // learner bin overflow (normally 0)
    for (int t2 = tid; t2 < m; t2 += 1024) {
        int e = (int)(jovf[t2] & 0xFFFFFu);
        int j = j_idx[e];
        if ((j >> 9) == b) atomicAdd(&ld[j & 511], outSv2[e]);
    }
    __syncthreads();
    if (tid < 512) {
        int node = b * 512 + tid;
        if (node < N_NODES) {
            float d = ld[tid];
            const float* pp = outS + node * KNN;
#pragma unroll
            for (int qq = 0; qq < KNN; qq++) d += pp[qq];
            dinv2[node] = (d > 0.0f) ? rsqrtf(fmaxf(d, 1e-12f)) : 0.0f;
        }
    }
}

// ---- final normalization: vals_norm = dinv2[r] * vals_s * dinv2[c] -------
__global__ void k_norm(const float* __restrict__ outS, const float* __restrict__ dinv2,
                       const int* __restrict__ j_idx, float* __restrict__ out) {
    int t = blockIdx.x * 256 + threadIdx.x;   // 2*NE threads
    int r, c;
    if (t < NE) { r = t / KNN; c = j_idx[t]; }
    else        { int e = t - NE; r = j_idx[e]; c = e / KNN; }
    out[t] = dinv2[r] * outS[t] * dinv2[c];
}

extern "C" void kernel_launch(void* const* d_in, const int* in_sizes, int n_in,
                              void* d_out, int out_size, void* d_ws, size_t ws_size,
                              hipStream_t stream) {
    const float* features = (const float*)d_in[0];
    const float* W1       = (const float*)d_in[1];
    const float* b1       = (const float*)d_in[2];
    const float* W2       = (const float*)d_in[3];
    const float* b2       = (const float*)d_in[4];
    const float* s_d      = (const float*)d_in[5];
    const int*   adj_row  = (const int*)d_in[6];
    const int*   adj_col  = (const int*)d_in[7];
    const int*   j_idx    = (const int*)d_in[9];
    float* out = (float*)d_out;

    const int N64 = N_NODES * 64;
    // Workspace layout (zero region first, all offsets 16B-aligned):
    // [cnt N][ovfcnts 16][bcnt 80][jbcnt 80]  <- memset 0
    // [dinv2 N][A N64 us][C N64 us][H N64 us]
    // [ebuf N*CAP us][ovf NE u][revb NE uc][bbuf][jbbuf][ovf2 NE u][jovf NE u]
    int*   cnt     = (int*)d_ws;
    int*   ovfcnts = cnt + N_NODES;          // [0]=CAP ovf, [4]=adj bin ovf, [8]=learner bin ovf
    int*   bcnt    = ovfcnts + 16;
    int*   jbcnt   = bcnt + NBUCK;
    float* dinv2   = (float*)(jbcnt + NBUCK);
    unsigned short* A   = (unsigned short*)(dinv2 + N_NODES);
    unsigned short* C   = A + N64;
    unsigned short* H   = C + N64;
    unsigned short* ebuf = H + N64;              // N*CAP ushorts
    unsigned* ovf    = (unsigned*)(ebuf + N_NODES * CAP);
    unsigned char* revb = (unsigned char*)(ovf + NE);
    unsigned* bbuf   = (unsigned*)(revb + NE);   // NBUCK*BCAP
    unsigned* jbbuf  = bbuf + NBUCK * BCAP;      // NBUCK*JBCAP
    unsigned* ovf2   = jbbuf + NBUCK * JBCAP;    // NE
    unsigned* jovf   = ovf2 + NE;                // NE

    // Re-init (ws is poisoned 0xAA before every call)
    size_t zero_bytes = (size_t)(N_NODES + 16 + 2 * NBUCK) * 4;
    hipMemsetAsync(cnt, 0, zero_bytes, stream);

    // Mega front end: gemm1 + bin(both sets) + reverse-edge scan (1 thr/edge)
    const int GB = N_NODES / 32;                          // 1250
    const int NBA = (NE + 256 * EPT - 1) / (256 * EPT);   // 469
    const int RB = NE / 256;                              // 3750
    k_mega1<<<GB + 2 * NBA + RB, 256, 0, stream>>>(
        features, W1, A, adj_row, adj_col, j_idx,
        bcnt, bbuf, ovf2, ovfcnts + 4, jbcnt, jbbuf, jovf, ovfcnts + 8, revb);

    // Per-bucket scatter (LDS slots, no global atomics) -> ebuf + cnt
    k_scatter3<<<NBUCK, 1024, 0, stream>>>(bbuf, bcnt, cnt, ebuf,
                                           ovf, ovfcnts, ovf2, ovfcnts + 4);

    // Fused layer-1: agg(A)+ReLU -> LDS -> xW2 -> C  (32 nodes/block)
    k_aggemm1<<<N_NODES / 32, 1024, 0, stream>>>(
        (const uint4*)A, W2, C, cnt, ebuf, b1, ovf, ovfcnts);

    // Layer-2 aggregate + normalize -> H  (2 nodes/wave, 32 lanes/node)
    k_aggf4<<<(N_NODES / 2 * 64 + 255) / 256, 256, 0, stream>>>(
        (const uint4*)C, (uint4*)H, cnt, ebuf, b2, ovf, ovfcnts);

    // Fused edge scores + symmetrize (atomic-free, 2 lanes/edge, 8 loads/lane)
    float* outS = out + 2 * NE;
    k_dotsym<<<NE * 2 / 256, 256, 0, stream>>>(
        (const uint4*)H, s_d, j_idx, revb, outS);

    // Binned in-edge accumulation + dinv2, then final normalize
    k_jagg<<<NBUCK, 1024, 0, stream>>>(jbbuf, jbcnt, outS, dinv2, jovf, ovfcnts + 8, j_idx);
    k_norm<<<2 * NE / 256, 256, 0, stream>>>(outS, dinv2, j_idx, out);
}